// Round 5
// baseline (112.692 us; speedup 1.0000x reference)
//
#include <hip/hip_runtime.h>
#include <hip/hip_bf16.h>

#define DD 256
#define NN 512

typedef __attribute__((ext_vector_type(8))) short short8;
typedef __attribute__((ext_vector_type(4))) float floatx4;

// ---- f32 -> bf16 round-to-nearest-even ----
__device__ __forceinline__ unsigned short f2bf(float f) {
  unsigned u = __float_as_uint(f);
  u += 0x7FFFu + ((u >> 16) & 1u);
  return (unsigned short)(u >> 16);
}
__device__ __forceinline__ unsigned pack2(float a, float b) {
  return (unsigned)f2bf(a) | ((unsigned)f2bf(b) << 16);
}

// ---------------------------------------------------------------------------
// MFMA fragment loader (global bf16 rows, k contiguous):
// lane holds X[row = lane&15][k = k0 + (lane>>4)*8 + j], j=0..7 -> one 16B load
// ---------------------------------------------------------------------------
__device__ __forceinline__ short8 ldfrag(const unsigned short* __restrict__ base,
                                         int row, int ld, int k, int lane) {
  return *(const short8*)(base + (row + (lane & 15)) * ld + k + ((lane >> 4) << 3));
}

template <int NF>
__device__ __forceinline__ void acc_zero(floatx4 acc[NF]) {
#pragma unroll
  for (int i = 0; i < NF; ++i) {
    acc[i][0] = 0.f; acc[i][1] = 0.f; acc[i][2] = 0.f; acc[i][3] = 0.f;
  }
}

// One wave accumulates C[16 x 16*NF] over K (multiple of 32).
template <int NF>
__device__ __forceinline__ void gemm_acc(floatx4 acc[NF],
    const unsigned short* __restrict__ A, int lda, int a_k0,
    const unsigned short* __restrict__ BT, int ldb, int b_k0,
    int K, int m0, int n0, int lane) {
  for (int k = 0; k < K; k += 32) {
    short8 a = ldfrag(A, m0, lda, a_k0 + k, lane);
#pragma unroll
    for (int nf = 0; nf < NF; ++nf) {
      short8 b = ldfrag(BT, n0 + nf * 16, ldb, b_k0 + k, lane);
      acc[nf] = __builtin_amdgcn_mfma_f32_16x16x32_bf16(a, b, acc[nf], 0, 0, 0);
    }
  }
}

// Split-K combine across 4 waves via LDS; wave 0 ends with the full sum.
// red = float[3 * 16 * 16*NF], layout [w-1][m(16)][n(16*NF)].
template <int NF>
__device__ __forceinline__ void ksplit_combine(floatx4 acc[NF], float* red,
                                               int wave, int lane) {
  const int W = 16 * NF;
  const int col = lane & 15;
  const int q = lane >> 4;
  if (wave > 0) {
    float* base = red + (wave - 1) * 16 * W;
#pragma unroll
    for (int nf = 0; nf < NF; ++nf)
#pragma unroll
      for (int r = 0; r < 4; ++r)
        base[(q * 4 + r) * W + nf * 16 + col] = acc[nf][r];
  }
  __syncthreads();
  if (wave == 0) {
#pragma unroll
    for (int nf = 0; nf < NF; ++nf)
#pragma unroll
      for (int r = 0; r < 4; ++r) {
        const int idx = (q * 4 + r) * W + nf * 16 + col;
        acc[nf][r] += red[idx] + red[16 * W + idx] + red[32 * W + idx];
      }
  }
}

// Epilogue for the C-layout (col = lane&15, row = (lane>>4)*4 + r).
template <int NF, bool COLBIAS, bool ROWBIAS, bool RELU, bool OUTBF>
__device__ __forceinline__ void gemm_epi(floatx4 acc[NF],
    const float* __restrict__ bias, void* __restrict__ C, int ldc,
    int m0, int n0, int lane) {
  const int col = lane & 15;
  const int q = lane >> 4;
#pragma unroll
  for (int nf = 0; nf < NF; ++nf) {
    const int n = n0 + nf * 16 + col;
    const float cb = COLBIAS ? bias[n] : 0.0f;
#pragma unroll
    for (int r = 0; r < 4; ++r) {
      const int m = m0 + q * 4 + r;
      float v = acc[nf][r] + cb + (ROWBIAS ? bias[m] : 0.0f);
      if (RELU) v = fmaxf(v, 0.0f);
      if (OUTBF) ((unsigned short*)C)[m * ldc + n] = f2bf(v);
      else       ((float*)C)[m * ldc + n] = v;
    }
  }
}

// ---------------------------------------------------------------------------
// prep: blocks 0..639 flat cvt (w1 128 | wa 256 | wb 128 | src 128)
//       blocks 640..895 transpose+cvt x,src -> xT,srcT [n][d]
//       blocks 896..1151 init sc_out = b2 (scores kernel atomicAdds onto it)
// ---------------------------------------------------------------------------
__global__ __launch_bounds__(256) void prep_kernel(
    const float* __restrict__ x, const float* __restrict__ src,
    const float* __restrict__ w1, const float* __restrict__ wa,
    const float* __restrict__ wb, const float* __restrict__ b2,
    unsigned short* __restrict__ w1b, unsigned short* __restrict__ wab,
    unsigned short* __restrict__ wbb, unsigned short* __restrict__ srcb,
    unsigned short* __restrict__ xT, unsigned short* __restrict__ srcT,
    float* __restrict__ sc) {
  const int bid = blockIdx.x;
  const int tid = threadIdx.x;
  if (bid < 640) {
    const float* in; unsigned short* out; int off;
    if (bid < 128)      { in = w1;  out = w1b; off = bid; }
    else if (bid < 384) { in = wa;  out = wab; off = bid - 128; }
    else if (bid < 512) { in = wb;  out = wbb; off = bid - 384; }
    else                { in = src; out = srcb; off = bid - 512; }
    const int i = off * 1024 + tid * 4;
    const float4 v = *(const float4*)(in + i);
    *(uint2*)(out + i) = make_uint2(pack2(v.x, v.y), pack2(v.z, v.w));
  } else if (bid < 896) {
    __shared__ float tile[32][33];
    const int b = bid - 640;
    const float* in = (b >> 7) ? src : x;
    unsigned short* out = (b >> 7) ? srcT : xT;
    const int t = b & 127;
    const int n0 = (t >> 3) * 32;
    const int d0 = (t & 7) * 32;
    const int tx = tid & 31, ty = tid >> 5;
#pragma unroll
    for (int i = ty; i < 32; i += 8)
      tile[i][tx] = in[(d0 + i) * NN + n0 + tx];
    __syncthreads();
#pragma unroll
    for (int i = ty; i < 32; i += 8)
      out[(n0 + i) * DD + d0 + tx] = f2bf(tile[tx][i]);
  } else {
    const float bv = b2[0];
    const int i = (bid - 896) * 1024 + tid * 4;
    float4 o; o.x = bv; o.y = bv; o.z = bv; o.w = bv;
    *(float4*)(sc + i) = o;
  }
}

// ---- aq[d][n] (+b1[d]) / ak[d][n], f32. A = w1 rows (k contig), BT = xT/srcT.
// grid (16 n-tiles of 32, 16 d-tiles, 2) = 512 blocks; 4 waves, split-K/4.
__global__ __launch_bounds__(256) void aqak_kernel(
    const unsigned short* __restrict__ xT, const unsigned short* __restrict__ srcT,
    const unsigned short* __restrict__ w1b, const float* __restrict__ b1,
    float* __restrict__ aq, float* __restrict__ ak) {
  __shared__ float red[1536];
  const int tid = threadIdx.x;
  const int lane = tid & 63;
  const int wave = tid >> 6;
  const int m0 = blockIdx.y * 16;   // d
  const int n0 = blockIdx.x * 32;   // token
  const int z = blockIdx.z;
  const unsigned short* BT = z ? srcT : xT;

  floatx4 acc[2]; acc_zero<2>(acc);
  gemm_acc<2>(acc, w1b, NN, z * 256 + wave * 64, BT, DD, wave * 64, 64, m0, n0, lane);
  ksplit_combine<2>(acc, red, wave, lane);
  if (wave == 0) {
    if (z == 0) gemm_epi<2, false, true, false, false>(acc, b1, aq, NN, m0, n0, lane);
    else        gemm_epi<2, false, false, false, false>(acc, nullptr, ak, NN, m0, n0, lane);
  }
}

// ---- scores: sc[n][m] += sum_{d in half z} w2[d] relu(aq[d][n] + ak[d][m])
// grid (16, 16, 2) = 512 blocks; f32 atomicAdd combine (sc pre-set to b2).
__global__ __launch_bounds__(256) void scores_kernel(
    const float* __restrict__ aq, const float* __restrict__ ak,
    const float* __restrict__ w2, float* __restrict__ sc) {
  __shared__ float aqs[128][32];
  __shared__ float aks[128][32];
  __shared__ float w2s[128];

  const int tid = threadIdx.x;
  const int n0 = blockIdx.x * 32;
  const int m0 = blockIdx.y * 32;
  const int d0 = blockIdx.z * 128;
  const int tn = tid & 31;
  const int tm4 = (tid >> 5) * 4;

  if (tid < 128) w2s[tid] = w2[d0 + tid];
#pragma unroll
  for (int k = 0; k < 16; ++k) {
    const int idx = k * 256 + tid;
    const int r = idx >> 5, cc = idx & 31;
    aqs[r][cc] = aq[(d0 + r) * NN + n0 + cc];
    aks[r][cc] = ak[(d0 + r) * NN + m0 + cc];
  }
  __syncthreads();

  float s0 = 0.f, s1 = 0.f, s2 = 0.f, s3 = 0.f;
  for (int dd = 0; dd < 128; ++dd) {
    const float w = w2s[dd];
    const float a = aqs[dd][tn];
    const float4 akv = *(const float4*)&aks[dd][tm4];
    s0 += w * fmaxf(a + akv.x, 0.f);
    s1 += w * fmaxf(a + akv.y, 0.f);
    s2 += w * fmaxf(a + akv.z, 0.f);
    s3 += w * fmaxf(a + akv.w, 0.f);
  }

  float* p = &sc[(n0 + tn) * NN + m0 + tm4];
  atomicAdd(p + 0, s0);
  atomicAdd(p + 1, s1);
  atomicAdd(p + 2, s2);
  atomicAdd(p + 3, s3);
}

// ---- msgT: softmax (rows n0..n0+15 of sc) fused with P @ src^T -------------
// msgT[n][d] = sum_m softmax(sc)[n][m] * src[d][m], bf16 out.
// grid (8 d-tiles of 32, 32 n-tiles) = 256 blocks; split-K/4 over m.
__global__ __launch_bounds__(256) void msgT_kernel(
    const float* __restrict__ sc, const unsigned short* __restrict__ srcb,
    unsigned short* __restrict__ msgTb) {
  __shared__ unsigned short Ap[16][520];   // [row][m], +8 pad (16B-aligned rows)
  __shared__ float red[1536];
  __shared__ float smax[16][16];
  __shared__ float ssum[16][16];
  __shared__ float rst[16][2];

  const int tid = threadIdx.x;
  const int lane = tid & 63;
  const int wave = tid >> 6;
  const int n0 = blockIdx.y * 16;   // token rows
  const int d0 = blockIdx.x * 32;   // d tile

  // ---------- softmax phase (coalesced: lane-minor m) ----------
  const int r = tid >> 4;      // 0..15 row
  const int c = tid & 15;      // float4 lane within 16-group
  float4 v[8];
  const float* rp = sc + (n0 + r) * NN + c * 4;
#pragma unroll
  for (int i = 0; i < 8; ++i) v[i] = *(const float4*)(rp + i * 64);

  float mx = -3.0e38f;
#pragma unroll
  for (int i = 0; i < 8; ++i)
    mx = fmaxf(mx, fmaxf(fmaxf(v[i].x, v[i].y), fmaxf(v[i].z, v[i].w)));
  smax[r][c] = mx;
  __syncthreads();
  if (c == 0) {
    float m2 = smax[r][0];
#pragma unroll
    for (int i = 1; i < 16; ++i) m2 = fmaxf(m2, smax[r][i]);
    rst[r][0] = m2;
  }
  __syncthreads();
  mx = rst[r][0];

  float sum = 0.f;
#pragma unroll
  for (int i = 0; i < 8; ++i) {
    v[i].x = __expf(v[i].x - mx); v[i].y = __expf(v[i].y - mx);
    v[i].z = __expf(v[i].z - mx); v[i].w = __expf(v[i].w - mx);
    sum += v[i].x + v[i].y + v[i].z + v[i].w;
  }
  ssum[r][c] = sum;
  __syncthreads();
  if (c == 0) {
    float s2 = ssum[r][0];
#pragma unroll
    for (int i = 1; i < 16; ++i) s2 += ssum[r][i];
    rst[r][1] = s2;
  }
  __syncthreads();
  const float inv = 1.0f / rst[r][1];
#pragma unroll
  for (int i = 0; i < 8; ++i) {
    *(unsigned*)&Ap[r][c * 4 + i * 64]     = pack2(v[i].x * inv, v[i].y * inv);
    *(unsigned*)&Ap[r][c * 4 + i * 64 + 2] = pack2(v[i].z * inv, v[i].w * inv);
  }
  __syncthreads();

  // ---------- GEMM phase (A from LDS, split-K/4 over m) ----------
  floatx4 acc[2]; acc_zero<2>(acc);
  const int k0w = wave * 128;
  const int arow = lane & 15;
  const int koff = (lane >> 4) << 3;
  for (int k = 0; k < 128; k += 32) {
    short8 a = *(const short8*)&Ap[arow][k0w + k + koff];
#pragma unroll
    for (int nf = 0; nf < 2; ++nf) {
      short8 b = ldfrag(srcb, d0 + nf * 16, NN, k0w + k, lane);
      acc[nf] = __builtin_amdgcn_mfma_f32_16x16x32_bf16(a, b, acc[nf], 0, 0, 0);
    }
  }
  ksplit_combine<2>(acc, red, wave, lane);
  if (wave == 0)
    gemm_epi<2, false, false, false, true>(acc, nullptr, msgTb, DD, n0, d0, lane);
}

// ---- h2T[n][o] = relu(xT@waL^T + msgT@waR^T + ba[o]), bf16 -----------------
// grid (16 o-tiles of 32, 32 n-tiles) = 512 blocks; split-K/4 over c=512.
__global__ __launch_bounds__(256) void h2T_kernel(
    const unsigned short* __restrict__ xT, const unsigned short* __restrict__ msgTb,
    const unsigned short* __restrict__ wab, const float* __restrict__ ba,
    unsigned short* __restrict__ h2Tb) {
  __shared__ float red[1536];
  const int tid = threadIdx.x;
  const int lane = tid & 63;
  const int wave = tid >> 6;
  const int m0 = blockIdx.y * 16;   // token
  const int n0 = blockIdx.x * 32;   // o

  floatx4 acc[2]; acc_zero<2>(acc);
  const unsigned short* A = (wave < 2) ? xT : msgTb;
  gemm_acc<2>(acc, A, DD, (wave & 1) * 128, wab, NN, wave * 128, 128, m0, n0, lane);
  ksplit_combine<2>(acc, red, wave, lane);
  if (wave == 0)
    gemm_epi<2, true, false, true, true>(acc, ba, h2Tb, NN, m0, n0, lane);
}

// ---- y[o][n] = wb @ relu-h2 + bb[o], f32 -----------------------------------
// grid (16 n-tiles of 32, 16 o-tiles) = 256 blocks; split-K/4 over 512.
__global__ __launch_bounds__(256) void y_kernel(
    const unsigned short* __restrict__ wbb, const unsigned short* __restrict__ h2Tb,
    const float* __restrict__ bb, float* __restrict__ y) {
  __shared__ float red[1536];
  const int tid = threadIdx.x;
  const int lane = tid & 63;
  const int wave = tid >> 6;
  const int m0 = blockIdx.y * 16;   // o
  const int n0 = blockIdx.x * 32;   // token

  floatx4 acc[2]; acc_zero<2>(acc);
  gemm_acc<2>(acc, wbb, NN, wave * 128, h2Tb, NN, wave * 128, 128, m0, n0, lane);
  ksplit_combine<2>(acc, red, wave, lane);
  if (wave == 0)
    gemm_epi<2, false, true, false, false>(acc, bb, y, NN, m0, n0, lane);
}

// ---------------------------------------------------------------------------
extern "C" void kernel_launch(void* const* d_in, const int* in_sizes, int n_in,
                              void* d_out, int out_size, void* d_ws, size_t ws_size,
                              hipStream_t stream) {
  (void)in_sizes; (void)n_in; (void)out_size; (void)ws_size;

  const float* x   = (const float*)d_in[0];
  const float* src = (const float*)d_in[1];
  const float* w1  = (const float*)d_in[2];
  const float* b1  = (const float*)d_in[3];
  const float* w2  = (const float*)d_in[4];
  const float* b2  = (const float*)d_in[5];
  const float* wa  = (const float*)d_in[6];
  const float* ba  = (const float*)d_in[7];
  const float* wb  = (const float*)d_in[8];
  const float* bb  = (const float*)d_in[9];

  float* y_out  = (float*)d_out;            // (256,512)
  float* sc_out = (float*)d_out + 131072;   // (512,512)

  char* ws = (char*)d_ws;
  unsigned short* w1b   = (unsigned short*)(ws);                 // 256KB
  unsigned short* wab   = (unsigned short*)(ws + (256 << 10));   // 512KB
  unsigned short* wbb   = (unsigned short*)(ws + (768 << 10));   // 256KB
  unsigned short* srcb  = (unsigned short*)(ws + (1024 << 10));  // 256KB
  unsigned short* xT    = (unsigned short*)(ws + (1280 << 10));  // 256KB
  unsigned short* srcT  = (unsigned short*)(ws + (1536 << 10));  // 256KB
  unsigned short* msgTb = (unsigned short*)(ws + (1792 << 10));  // 256KB
  unsigned short* h2Tb  = (unsigned short*)(ws + (2048 << 10));  // 512KB
  float*          aq    = (float*)(ws + (2560 << 10));           // 512KB
  float*          ak    = (float*)(ws + (3072 << 10));           // 512KB

  prep_kernel<<<1152, 256, 0, stream>>>(x, src, w1, wa, wb, b2,
                                        w1b, wab, wbb, srcb, xT, srcT, sc_out);
  aqak_kernel<<<dim3(16, 16, 2), 256, 0, stream>>>(xT, srcT, w1b, b1, aq, ak);
  scores_kernel<<<dim3(16, 16, 2), 256, 0, stream>>>(aq, ak, w2, sc_out);
  msgT_kernel<<<dim3(8, 32), 256, 0, stream>>>(sc_out, srcb, msgTb);
  h2T_kernel<<<dim3(16, 32), 256, 0, stream>>>(xT, msgTb, wab, ba, h2Tb);
  y_kernel<<<dim3(16, 16), 256, 0, stream>>>(wbb, h2Tb, bb, y_out);
}